// Round 17
// baseline (129.752 us; speedup 1.0000x reference)
//
#include <hip/hip_runtime.h>
#include <stdint.h>

#define N_NODES 50000
#define N_EDGES 400000
#define DDIM 256
#define MASK_WORDS 400000  // 50000*256/32
#define EDGE_CAP 64        // padded CSR row capacity (max in-degree ~30)
#define EDGE_BLOCKS 782    // ceil(400000/2/256), 2 edges per thread
#define MASK_BLOCKS 1563   // ceil(400000/256)
#define FCONV_BLOCKS 6250  // 50000*256/8 / 256

typedef __attribute__((ext_vector_type(8))) short bf16x8;
typedef __attribute__((ext_vector_type(4))) float f32x4;

// ---------------------------------------------------------------------------
// JAX threefry2x32, key = (0, 42).  Partitionable scheme (verified round 5):
// element with flat index j uses counter (0, j); draw = out0 ^ out1.
// ---------------------------------------------------------------------------
__device__ __forceinline__ uint32_t rotl32(uint32_t x, uint32_t r) {
  return (x << r) | (x >> (32u - r));
}

__device__ __forceinline__ uint32_t threefry_draw_0_42(uint32_t x0, uint32_t x1) {
  const uint32_t k0 = 0u, k1 = 42u;
  const uint32_t k2 = k0 ^ k1 ^ 0x1BD11BDAu;
  x0 += k0;
  x1 += k1;
#define TF_ROUND(r)          \
  {                          \
    x0 += x1;                \
    x1 = rotl32(x1, r);      \
    x1 ^= x0;                \
  }
  TF_ROUND(13) TF_ROUND(15) TF_ROUND(26) TF_ROUND(6)
  x0 += k1; x1 += k2 + 1u;
  TF_ROUND(17) TF_ROUND(29) TF_ROUND(16) TF_ROUND(24)
  x0 += k2; x1 += k0 + 2u;
  TF_ROUND(13) TF_ROUND(15) TF_ROUND(26) TF_ROUND(6)
  x0 += k0; x1 += k1 + 3u;
  TF_ROUND(17) TF_ROUND(29) TF_ROUND(16) TF_ROUND(24)
  x0 += k1; x1 += k2 + 4u;
  TF_ROUND(13) TF_ROUND(15) TF_ROUND(26) TF_ROUND(6)
  x0 += k2; x1 += k0 + 5u;
#undef TF_ROUND
  return x0 ^ x1;
}

__device__ __forceinline__ uint16_t bf16_rne(float x) {
  uint32_t u = __float_as_uint(x);
  u += 0x7FFFu + ((u >> 16) & 1u);
  return (uint16_t)(u >> 16);
}

// ---------------------------------------------------------------------------
// 1) setup: blocks 0-97 zero deg_out+deg_in (25000 int4);
//           blocks 98-161 transpose W fp32 [k][n] -> Wt bf16 [n][k]
// ---------------------------------------------------------------------------
__global__ __launch_bounds__(256) void setup_kernel(
    const float* __restrict__ W, uint16_t* __restrict__ Wt,
    int4* __restrict__ zero_base) {
  const int bid = blockIdx.x;
  if (bid < 98) {
    const int t = bid * 256 + threadIdx.x;
    if (t < 25000) zero_base[t] = make_int4(0, 0, 0, 0);
  } else {
    const int t = (bid - 98) * 256 + threadIdx.x;  // 0..16383
    const int n = t >> 6;
    const int k4 = (t & 63) << 2;
    ushort4 p;
    p.x = bf16_rne(W[(size_t)(k4 + 0) * DDIM + n]);
    p.y = bf16_rne(W[(size_t)(k4 + 1) * DDIM + n]);
    p.z = bf16_rne(W[(size_t)(k4 + 2) * DDIM + n]);
    p.w = bf16_rne(W[(size_t)(k4 + 3) * DDIM + n]);
    *(ushort4*)(Wt + (size_t)n * DDIM + k4) = p;
  }
}

// ---------------------------------------------------------------------------
// 2) MEGA-FUSED prep.  Block ranges (latency-bound edges FIRST):
//      [0, 782)              edge pass, 2 edges/thread: deg_out histogram
//                            (no-return atomic) + deg_in cursor + esrc store
//      [782, 2345)           dropout bitmask (pure VALU)
//      [2345, 8595)          featb = bf16(feat)  (pure convert, BW-bound)
//    Disjoint outputs; no section reads another's output.
// ---------------------------------------------------------------------------
__global__ __launch_bounds__(256) void mega_prep_kernel(
    const float* __restrict__ feat, const int* __restrict__ src,
    const int* __restrict__ dst, int* __restrict__ deg_out,
    int* __restrict__ deg_in, int* __restrict__ esrc,
    uint32_t* __restrict__ mask, uint16_t* __restrict__ featb) {
  const int bid = blockIdx.x;
  if (bid < EDGE_BLOCKS) {
    const int base = (bid * 256 + threadIdx.x) * 2;
    if (base < N_EDGES) {  // N_EDGES%2==0 -> full int2 in bounds
      const int2 s2 = *(const int2*)(src + base);
      const int2 d2 = *(const int2*)(dst + base);
      atomicAdd(&deg_out[s2.x], 1);
      atomicAdd(&deg_out[s2.y], 1);
      const int p0 = atomicAdd(&deg_in[d2.x], 1);
      const int p1 = atomicAdd(&deg_in[d2.y], 1);
      if (p0 < EDGE_CAP) esrc[(d2.x << 6) + p0] = s2.x;
      if (p1 < EDGE_CAP) esrc[(d2.y << 6) + p1] = s2.y;
    }
  } else if (bid < EDGE_BLOCKS + MASK_BLOCKS) {
    // dropout bitmask; keep(j) <=> (draw>>9) < 7549747 (== u<0.9f exactly)
    const uint32_t t =
        (uint32_t)(bid - EDGE_BLOCKS) * 256u + (uint32_t)threadIdx.x;
    if (t < MASK_WORDS) {
      const uint32_t base = t * 32u;
      uint32_t w = 0u;
#pragma unroll
      for (uint32_t b = 0; b < 32u; ++b) {
        const uint32_t bits = threefry_draw_0_42(0u, base + b);
        w |= ((bits >> 9) < 7549747u) ? (1u << b) : 0u;
      }
      mask[t] = w;
    }
  } else {
    // featb = bf16(feat)  (unscaled; gather applies rsqrt(deg_out) per edge)
    const int t = (bid - EDGE_BLOCKS - MASK_BLOCKS) * 256 + threadIdx.x;
    const size_t base = (size_t)t * 8;
    const float4 a = *(const float4*)(feat + base);
    const float4 b = *(const float4*)(feat + base + 4);
    ushort4 lo, hi;
    lo.x = bf16_rne(a.x); lo.y = bf16_rne(a.y);
    lo.z = bf16_rne(a.z); lo.w = bf16_rne(a.w);
    hi.x = bf16_rne(b.x); hi.y = bf16_rne(b.y);
    hi.z = bf16_rne(b.z); hi.w = bf16_rne(b.w);
    *(ushort4*)(featb + base) = lo;
    *(ushort4*)(featb + base + 4) = hi;
  }
}

// ---------------------------------------------------------------------------
// 3) pull-mode aggregate: FULL wave (64 lanes) per node; lane owns 4 bf16
//    (uint2, 8B) of the 256-col row -> 50K waves (2x round-16 TLP).
//    8 edge rows + their deg scales issued back-to-back, fp32 fma
//    accumulate; 4/2/1 ladder tail.  scale = rsqrt(max(deg_out[src],1)).
// ---------------------------------------------------------------------------
__device__ __forceinline__ void acc4s(float* a, uint2 q, float sc) {
  a[0] = fmaf(__uint_as_float(q.x << 16), sc, a[0]);
  a[1] = fmaf(__uint_as_float(q.x & 0xFFFF0000u), sc, a[1]);
  a[2] = fmaf(__uint_as_float(q.y << 16), sc, a[2]);
  a[3] = fmaf(__uint_as_float(q.y & 0xFFFF0000u), sc, a[3]);
}

__device__ __forceinline__ float dscale(const int* deg, int s) {
  return rsqrtf(fmaxf((float)deg[s], 1.0f));
}

__global__ __launch_bounds__(256) void gather_kernel(
    const uint16_t* __restrict__ featb, const int* __restrict__ deg_out,
    const int* __restrict__ deg_in, const int* __restrict__ esrc,
    uint16_t* __restrict__ agg) {
  const int n = blockIdx.x * 4 + (threadIdx.x >> 6);
  if (n >= N_NODES) return;
  const int lane = threadIdx.x & 63;
  const size_t coff = (size_t)(lane << 2);  // 4 bf16 = 8 B per lane
  const int beg = n << 6;
  const int cnt = min(deg_in[n], EDGE_CAP);

  float a[4] = {};
  int j = 0;
  for (; j + 8 <= cnt; j += 8) {
    const int4 e0 = *(const int4*)(esrc + beg + j);
    const int4 e1 = *(const int4*)(esrc + beg + j + 4);
    const uint2 q0 = *(const uint2*)(featb + (size_t)e0.x * DDIM + coff);
    const uint2 q1 = *(const uint2*)(featb + (size_t)e0.y * DDIM + coff);
    const uint2 q2 = *(const uint2*)(featb + (size_t)e0.z * DDIM + coff);
    const uint2 q3 = *(const uint2*)(featb + (size_t)e0.w * DDIM + coff);
    const uint2 q4 = *(const uint2*)(featb + (size_t)e1.x * DDIM + coff);
    const uint2 q5 = *(const uint2*)(featb + (size_t)e1.y * DDIM + coff);
    const uint2 q6 = *(const uint2*)(featb + (size_t)e1.z * DDIM + coff);
    const uint2 q7 = *(const uint2*)(featb + (size_t)e1.w * DDIM + coff);
    const float s0 = dscale(deg_out, e0.x);
    const float s1 = dscale(deg_out, e0.y);
    const float s2 = dscale(deg_out, e0.z);
    const float s3 = dscale(deg_out, e0.w);
    const float s4 = dscale(deg_out, e1.x);
    const float s5 = dscale(deg_out, e1.y);
    const float s6 = dscale(deg_out, e1.z);
    const float s7 = dscale(deg_out, e1.w);
    acc4s(a, q0, s0); acc4s(a, q1, s1); acc4s(a, q2, s2); acc4s(a, q3, s3);
    acc4s(a, q4, s4); acc4s(a, q5, s5); acc4s(a, q6, s6); acc4s(a, q7, s7);
  }
  if (j + 4 <= cnt) {
    const int4 e0 = *(const int4*)(esrc + beg + j);
    const uint2 q0 = *(const uint2*)(featb + (size_t)e0.x * DDIM + coff);
    const uint2 q1 = *(const uint2*)(featb + (size_t)e0.y * DDIM + coff);
    const uint2 q2 = *(const uint2*)(featb + (size_t)e0.z * DDIM + coff);
    const uint2 q3 = *(const uint2*)(featb + (size_t)e0.w * DDIM + coff);
    const float s0 = dscale(deg_out, e0.x);
    const float s1 = dscale(deg_out, e0.y);
    const float s2 = dscale(deg_out, e0.z);
    const float s3 = dscale(deg_out, e0.w);
    acc4s(a, q0, s0); acc4s(a, q1, s1); acc4s(a, q2, s2); acc4s(a, q3, s3);
    j += 4;
  }
  if (j + 2 <= cnt) {
    const int s0i = esrc[beg + j];
    const int s1i = esrc[beg + j + 1];
    const uint2 q0 = *(const uint2*)(featb + (size_t)s0i * DDIM + coff);
    const uint2 q1 = *(const uint2*)(featb + (size_t)s1i * DDIM + coff);
    acc4s(a, q0, dscale(deg_out, s0i));
    acc4s(a, q1, dscale(deg_out, s1i));
    j += 2;
  }
  if (j < cnt) {
    const int s0i = esrc[beg + j];
    const uint2 q0 = *(const uint2*)(featb + (size_t)s0i * DDIM + coff);
    acc4s(a, q0, dscale(deg_out, s0i));
  }

  uint2 p;
  p.x = (uint32_t)bf16_rne(a[0]) | ((uint32_t)bf16_rne(a[1]) << 16);
  p.y = (uint32_t)bf16_rne(a[2]) | ((uint32_t)bf16_rne(a[3]) << 16);
  *(uint2*)(agg + (size_t)n * DDIM + coff) = p;
}

// ---------------------------------------------------------------------------
// 4) out = dropout(relu((agg @ W) * rsqrt(max(deg_in,1)) + b))
//    MFMA bf16 16x16x32.  Block = 64 rows x 256 cols, 4 waves (wave: 64x64).
//    A staged once in LDS (37 KB -> 4 blocks/CU); B direct from L2 Wt.
// ---------------------------------------------------------------------------
#define APAD 280  // shorts per As row (560 B, 16B-aligned)
__global__ __launch_bounds__(256, 4) void gemm_mfma_kernel(
    const uint16_t* __restrict__ agg, const uint16_t* __restrict__ Wt,
    const float* __restrict__ bias, const int* __restrict__ deg_in,
    const uint32_t* __restrict__ mask, float* __restrict__ out) {
  __shared__ short As[64 * APAD];
  __shared__ float sdeg[64];
  __shared__ float sbias[256];

  const int tid = threadIdx.x;
  const int r0 = blockIdx.x * 64;
  const int lane = tid & 63;
  const int seg = lane >> 4;  // k-segment 0..3
  const int l15 = lane & 15;
  const int wc = tid >> 6;  // wave -> col panel (64 cols each)

  sbias[tid] = bias[tid];
  if (tid < 64) {
    const int r = r0 + tid;
    sdeg[tid] = (r < N_NODES) ? rsqrtf(fmaxf((float)deg_in[r], 1.0f)) : 0.0f;
  }

  // stage A panel: 64 rows x 256 k bf16 (2048 x 16B chunks, coalesced)
  {
    const uint16_t* ap = agg + (size_t)r0 * DDIM;
#pragma unroll
    for (int it = 0; it < 8; ++it) {
      const int c = tid + 256 * it;
      const int row = c >> 5;        // 32 chunks per row
      const int k8 = (c & 31) << 3;  // 0,8,...,248
      int4 v = make_int4(0, 0, 0, 0);
      if (r0 + row < N_NODES) v = *(const int4*)(ap + (size_t)row * DDIM + k8);
      *(int4*)&As[row * APAD + k8] = v;
    }
  }
  __syncthreads();

  const uint16_t* wt_base = Wt + (size_t)(wc * 64 + l15) * DDIM + seg * 8;

  f32x4 acc[4][4] = {};
#pragma unroll
  for (int kkI = 0; kkI < 8; ++kkI) {
    const int kk = kkI * 32;
    bf16x8 a[4], b[4];
#pragma unroll
    for (int m = 0; m < 4; ++m)
      a[m] = *(const bf16x8*)&As[(m * 16 + l15) * APAD + kk + seg * 8];
#pragma unroll
    for (int n = 0; n < 4; ++n)
      b[n] = *(const bf16x8*)(wt_base + n * 16 * DDIM + kk);
#pragma unroll
    for (int m = 0; m < 4; ++m)
#pragma unroll
      for (int n = 0; n < 4; ++n)
        acc[m][n] = __builtin_amdgcn_mfma_f32_16x16x32_bf16(a[m], b[n], acc[m][n], 0, 0, 0);
  }

  // epilogue: C/D layout col = lane&15, row = seg*4 + reg
  constexpr float INV09 = 1.0f / 0.9f;
#pragma unroll
  for (int m = 0; m < 4; ++m) {
#pragma unroll
    for (int r = 0; r < 4; ++r) {
      const int lrow = m * 16 + seg * 4 + r;
      const int row = r0 + lrow;
      if (row >= N_NODES) continue;
      const float s = sdeg[lrow];
      const uint32_t w0 = mask[row * 8 + wc * 2];      // cols wc*64 .. +31
      const uint32_t w1 = mask[row * 8 + wc * 2 + 1];  // cols wc*64+32 .. +63
#pragma unroll
      for (int n = 0; n < 4; ++n) {
        const int col = wc * 64 + n * 16 + l15;
        float v = fmaxf(acc[m][n][r] * s + sbias[col], 0.0f);
        const uint32_t w = (n < 2) ? w0 : w1;
        const uint32_t bit = (uint32_t)((n & 1) * 16 + l15);
        out[(size_t)row * DDIM + col] = ((w >> bit) & 1u) ? v * INV09 : 0.0f;
      }
    }
  }
}

// ---------------------------------------------------------------------------
// ws layout (bytes; ws_size ~268 MB per harness poison fill):
//   deg_out   @ 0          (200000)
//   deg_in    @ 200000     (200000)
//   esrc      @ 400000     (12800000)  padded CSR [n][64]
//   Wt bf16   @ 13200000   (131072)
//   featb bf16@ 13331072   (25600000)
//   mask u32  @ 38931072   (1600000)
//   agg bf16  @ 40531072   (25600000)  total ~66 MB
// ---------------------------------------------------------------------------
extern "C" void kernel_launch(void* const* d_in, const int* in_sizes, int n_in,
                              void* d_out, int out_size, void* d_ws, size_t ws_size,
                              hipStream_t stream) {
  const float* feat = (const float*)d_in[0];
  const float* W = (const float*)d_in[1];
  const float* bias = (const float*)d_in[2];
  const int* src = (const int*)d_in[3];
  const int* dst = (const int*)d_in[4];
  float* out = (float*)d_out;

  char* ws = (char*)d_ws;
  int* deg_out = (int*)(ws + 0);
  int* deg_in = (int*)(ws + 200000);
  int* esrc = (int*)(ws + 400000);
  uint16_t* Wt = (uint16_t*)(ws + 13200000);
  uint16_t* featb = (uint16_t*)(ws + 13331072);
  uint32_t* mask = (uint32_t*)(ws + 38931072);
  uint16_t* agg = (uint16_t*)(ws + 40531072);

  setup_kernel<<<162, 256, 0, stream>>>(W, Wt, (int4*)d_ws);
  mega_prep_kernel<<<EDGE_BLOCKS + MASK_BLOCKS + FCONV_BLOCKS, 256, 0, stream>>>(
      feat, src, dst, deg_out, deg_in, esrc, mask, featb);
  gather_kernel<<<(N_NODES + 3) / 4, 256, 0, stream>>>(featb, deg_out, deg_in, esrc, agg);
  gemm_mfma_kernel<<<(N_NODES + 63) / 64, 256, 0, stream>>>(agg, Wt, bias, deg_in, mask, out);
}

// Round 18
// 114.808 us; speedup vs baseline: 1.1302x; 1.1302x over previous
//
#include <hip/hip_runtime.h>
#include <stdint.h>

#define N_NODES 50000
#define N_EDGES 400000
#define DDIM 256
#define MASK_WORDS 400000  // 50000*256/32
#define EDGE_CAP 64        // padded CSR row capacity (max in-degree ~30)
#define EDGE_BLOCKS 391    // ceil(400000/4/256), 4 edges per thread (r16 best)
#define MASK_BLOCKS 1563   // ceil(400000/256)
#define FCONV_BLOCKS 6250  // 50000*256/8 / 256

typedef __attribute__((ext_vector_type(8))) short bf16x8;
typedef __attribute__((ext_vector_type(4))) float f32x4;

// ---------------------------------------------------------------------------
// JAX threefry2x32, key = (0, 42).  Partitionable scheme (verified round 5):
// element with flat index j uses counter (0, j); draw = out0 ^ out1.
// ---------------------------------------------------------------------------
__device__ __forceinline__ uint32_t rotl32(uint32_t x, uint32_t r) {
  return (x << r) | (x >> (32u - r));
}

__device__ __forceinline__ uint32_t threefry_draw_0_42(uint32_t x0, uint32_t x1) {
  const uint32_t k0 = 0u, k1 = 42u;
  const uint32_t k2 = k0 ^ k1 ^ 0x1BD11BDAu;
  x0 += k0;
  x1 += k1;
#define TF_ROUND(r)          \
  {                          \
    x0 += x1;                \
    x1 = rotl32(x1, r);      \
    x1 ^= x0;                \
  }
  TF_ROUND(13) TF_ROUND(15) TF_ROUND(26) TF_ROUND(6)
  x0 += k1; x1 += k2 + 1u;
  TF_ROUND(17) TF_ROUND(29) TF_ROUND(16) TF_ROUND(24)
  x0 += k2; x1 += k0 + 2u;
  TF_ROUND(13) TF_ROUND(15) TF_ROUND(26) TF_ROUND(6)
  x0 += k0; x1 += k1 + 3u;
  TF_ROUND(17) TF_ROUND(29) TF_ROUND(16) TF_ROUND(24)
  x0 += k1; x1 += k2 + 4u;
  TF_ROUND(13) TF_ROUND(15) TF_ROUND(26) TF_ROUND(6)
  x0 += k2; x1 += k0 + 5u;
#undef TF_ROUND
  return x0 ^ x1;
}

__device__ __forceinline__ uint16_t bf16_rne(float x) {
  uint32_t u = __float_as_uint(x);
  u += 0x7FFFu + ((u >> 16) & 1u);
  return (uint16_t)(u >> 16);
}

// ---------------------------------------------------------------------------
// 1) setup: blocks 0-97 zero deg_out+deg_in (25000 int4);
//           blocks 98-161 transpose W fp32 [k][n] -> Wt bf16 [n][k]
// ---------------------------------------------------------------------------
__global__ __launch_bounds__(256) void setup_kernel(
    const float* __restrict__ W, uint16_t* __restrict__ Wt,
    int4* __restrict__ zero_base) {
  const int bid = blockIdx.x;
  if (bid < 98) {
    const int t = bid * 256 + threadIdx.x;
    if (t < 25000) zero_base[t] = make_int4(0, 0, 0, 0);
  } else {
    const int t = (bid - 98) * 256 + threadIdx.x;  // 0..16383
    const int n = t >> 6;
    const int k4 = (t & 63) << 2;
    ushort4 p;
    p.x = bf16_rne(W[(size_t)(k4 + 0) * DDIM + n]);
    p.y = bf16_rne(W[(size_t)(k4 + 1) * DDIM + n]);
    p.z = bf16_rne(W[(size_t)(k4 + 2) * DDIM + n]);
    p.w = bf16_rne(W[(size_t)(k4 + 3) * DDIM + n]);
    *(ushort4*)(Wt + (size_t)n * DDIM + k4) = p;
  }
}

// ---------------------------------------------------------------------------
// 2) MEGA-FUSED prep.  Block ranges (latency-bound edges FIRST):
//      [0, 391)              edge pass, 4 edges/thread (int4 loads; 8
//                            independent atomic chains/thread — r16-proven):
//                            deg_out histogram + deg_in cursor + esrc store
//      [391, 1954)           dropout bitmask (pure VALU)
//      [1954, 8204)          featb = bf16(feat)  (pure convert, BW-bound)
//    Disjoint outputs; no section reads another's output.
// ---------------------------------------------------------------------------
__global__ __launch_bounds__(256) void mega_prep_kernel(
    const float* __restrict__ feat, const int* __restrict__ src,
    const int* __restrict__ dst, int* __restrict__ deg_out,
    int* __restrict__ deg_in, int* __restrict__ esrc,
    uint32_t* __restrict__ mask, uint16_t* __restrict__ featb) {
  const int bid = blockIdx.x;
  if (bid < EDGE_BLOCKS) {
    const int base = (bid * 256 + threadIdx.x) * 4;
    if (base < N_EDGES) {  // N_EDGES%4==0 -> full int4 in bounds
      const int4 s4 = *(const int4*)(src + base);
      const int4 d4 = *(const int4*)(dst + base);
      atomicAdd(&deg_out[s4.x], 1);
      atomicAdd(&deg_out[s4.y], 1);
      atomicAdd(&deg_out[s4.z], 1);
      atomicAdd(&deg_out[s4.w], 1);
      const int p0 = atomicAdd(&deg_in[d4.x], 1);
      const int p1 = atomicAdd(&deg_in[d4.y], 1);
      const int p2 = atomicAdd(&deg_in[d4.z], 1);
      const int p3 = atomicAdd(&deg_in[d4.w], 1);
      if (p0 < EDGE_CAP) esrc[(d4.x << 6) + p0] = s4.x;
      if (p1 < EDGE_CAP) esrc[(d4.y << 6) + p1] = s4.y;
      if (p2 < EDGE_CAP) esrc[(d4.z << 6) + p2] = s4.z;
      if (p3 < EDGE_CAP) esrc[(d4.w << 6) + p3] = s4.w;
    }
  } else if (bid < EDGE_BLOCKS + MASK_BLOCKS) {
    // dropout bitmask; keep(j) <=> (draw>>9) < 7549747 (== u<0.9f exactly)
    const uint32_t t =
        (uint32_t)(bid - EDGE_BLOCKS) * 256u + (uint32_t)threadIdx.x;
    if (t < MASK_WORDS) {
      const uint32_t base = t * 32u;
      uint32_t w = 0u;
#pragma unroll
      for (uint32_t b = 0; b < 32u; ++b) {
        const uint32_t bits = threefry_draw_0_42(0u, base + b);
        w |= ((bits >> 9) < 7549747u) ? (1u << b) : 0u;
      }
      mask[t] = w;
    }
  } else {
    // featb = bf16(feat)  (unscaled; gather applies rsqrt(deg_out) per edge)
    const int t = (bid - EDGE_BLOCKS - MASK_BLOCKS) * 256 + threadIdx.x;
    const size_t base = (size_t)t * 8;
    const float4 a = *(const float4*)(feat + base);
    const float4 b = *(const float4*)(feat + base + 4);
    ushort4 lo, hi;
    lo.x = bf16_rne(a.x); lo.y = bf16_rne(a.y);
    lo.z = bf16_rne(a.z); lo.w = bf16_rne(a.w);
    hi.x = bf16_rne(b.x); hi.y = bf16_rne(b.y);
    hi.z = bf16_rne(b.z); hi.w = bf16_rne(b.w);
    *(ushort4*)(featb + base) = lo;
    *(ushort4*)(featb + base + 4) = hi;
  }
}

// ---------------------------------------------------------------------------
// 3) pull-mode aggregate: FULL wave (64 lanes) per node; lane owns 4 bf16
//    (uint2, 8B) of the 256-col row -> 50K waves (r17-proven better).
//    8 edge rows + their deg scales issued back-to-back, fp32 fma
//    accumulate; 4/2/1 ladder tail.  scale = rsqrt(max(deg_out[src],1)).
// ---------------------------------------------------------------------------
__device__ __forceinline__ void acc4s(float* a, uint2 q, float sc) {
  a[0] = fmaf(__uint_as_float(q.x << 16), sc, a[0]);
  a[1] = fmaf(__uint_as_float(q.x & 0xFFFF0000u), sc, a[1]);
  a[2] = fmaf(__uint_as_float(q.y << 16), sc, a[2]);
  a[3] = fmaf(__uint_as_float(q.y & 0xFFFF0000u), sc, a[3]);
}

__device__ __forceinline__ float dscale(const int* deg, int s) {
  return rsqrtf(fmaxf((float)deg[s], 1.0f));
}

__global__ __launch_bounds__(256) void gather_kernel(
    const uint16_t* __restrict__ featb, const int* __restrict__ deg_out,
    const int* __restrict__ deg_in, const int* __restrict__ esrc,
    uint16_t* __restrict__ agg) {
  const int n = blockIdx.x * 4 + (threadIdx.x >> 6);
  if (n >= N_NODES) return;
  const int lane = threadIdx.x & 63;
  const size_t coff = (size_t)(lane << 2);  // 4 bf16 = 8 B per lane
  const int beg = n << 6;
  const int cnt = min(deg_in[n], EDGE_CAP);

  float a[4] = {};
  int j = 0;
  for (; j + 8 <= cnt; j += 8) {
    const int4 e0 = *(const int4*)(esrc + beg + j);
    const int4 e1 = *(const int4*)(esrc + beg + j + 4);
    const uint2 q0 = *(const uint2*)(featb + (size_t)e0.x * DDIM + coff);
    const uint2 q1 = *(const uint2*)(featb + (size_t)e0.y * DDIM + coff);
    const uint2 q2 = *(const uint2*)(featb + (size_t)e0.z * DDIM + coff);
    const uint2 q3 = *(const uint2*)(featb + (size_t)e0.w * DDIM + coff);
    const uint2 q4 = *(const uint2*)(featb + (size_t)e1.x * DDIM + coff);
    const uint2 q5 = *(const uint2*)(featb + (size_t)e1.y * DDIM + coff);
    const uint2 q6 = *(const uint2*)(featb + (size_t)e1.z * DDIM + coff);
    const uint2 q7 = *(const uint2*)(featb + (size_t)e1.w * DDIM + coff);
    const float s0 = dscale(deg_out, e0.x);
    const float s1 = dscale(deg_out, e0.y);
    const float s2 = dscale(deg_out, e0.z);
    const float s3 = dscale(deg_out, e0.w);
    const float s4 = dscale(deg_out, e1.x);
    const float s5 = dscale(deg_out, e1.y);
    const float s6 = dscale(deg_out, e1.z);
    const float s7 = dscale(deg_out, e1.w);
    acc4s(a, q0, s0); acc4s(a, q1, s1); acc4s(a, q2, s2); acc4s(a, q3, s3);
    acc4s(a, q4, s4); acc4s(a, q5, s5); acc4s(a, q6, s6); acc4s(a, q7, s7);
  }
  if (j + 4 <= cnt) {
    const int4 e0 = *(const int4*)(esrc + beg + j);
    const uint2 q0 = *(const uint2*)(featb + (size_t)e0.x * DDIM + coff);
    const uint2 q1 = *(const uint2*)(featb + (size_t)e0.y * DDIM + coff);
    const uint2 q2 = *(const uint2*)(featb + (size_t)e0.z * DDIM + coff);
    const uint2 q3 = *(const uint2*)(featb + (size_t)e0.w * DDIM + coff);
    const float s0 = dscale(deg_out, e0.x);
    const float s1 = dscale(deg_out, e0.y);
    const float s2 = dscale(deg_out, e0.z);
    const float s3 = dscale(deg_out, e0.w);
    acc4s(a, q0, s0); acc4s(a, q1, s1); acc4s(a, q2, s2); acc4s(a, q3, s3);
    j += 4;
  }
  if (j + 2 <= cnt) {
    const int s0i = esrc[beg + j];
    const int s1i = esrc[beg + j + 1];
    const uint2 q0 = *(const uint2*)(featb + (size_t)s0i * DDIM + coff);
    const uint2 q1 = *(const uint2*)(featb + (size_t)s1i * DDIM + coff);
    acc4s(a, q0, dscale(deg_out, s0i));
    acc4s(a, q1, dscale(deg_out, s1i));
    j += 2;
  }
  if (j < cnt) {
    const int s0i = esrc[beg + j];
    const uint2 q0 = *(const uint2*)(featb + (size_t)s0i * DDIM + coff);
    acc4s(a, q0, dscale(deg_out, s0i));
  }

  uint2 p;
  p.x = (uint32_t)bf16_rne(a[0]) | ((uint32_t)bf16_rne(a[1]) << 16);
  p.y = (uint32_t)bf16_rne(a[2]) | ((uint32_t)bf16_rne(a[3]) << 16);
  *(uint2*)(agg + (size_t)n * DDIM + coff) = p;
}

// ---------------------------------------------------------------------------
// 4) out = dropout(relu((agg @ W) * rsqrt(max(deg_in,1)) + b))
//    MFMA bf16 16x16x32.  Block = 64 rows x 256 cols, 4 waves (wave: 64x64).
//    A staged once in LDS (37 KB -> 4 blocks/CU); B direct from L2 Wt.
// ---------------------------------------------------------------------------
#define APAD 280  // shorts per As row (560 B, 16B-aligned)
__global__ __launch_bounds__(256, 4) void gemm_mfma_kernel(
    const uint16_t* __restrict__ agg, const uint16_t* __restrict__ Wt,
    const float* __restrict__ bias, const int* __restrict__ deg_in,
    const uint32_t* __restrict__ mask, float* __restrict__ out) {
  __shared__ short As[64 * APAD];
  __shared__ float sdeg[64];
  __shared__ float sbias[256];

  const int tid = threadIdx.x;
  const int r0 = blockIdx.x * 64;
  const int lane = tid & 63;
  const int seg = lane >> 4;  // k-segment 0..3
  const int l15 = lane & 15;
  const int wc = tid >> 6;  // wave -> col panel (64 cols each)

  sbias[tid] = bias[tid];
  if (tid < 64) {
    const int r = r0 + tid;
    sdeg[tid] = (r < N_NODES) ? rsqrtf(fmaxf((float)deg_in[r], 1.0f)) : 0.0f;
  }

  // stage A panel: 64 rows x 256 k bf16 (2048 x 16B chunks, coalesced)
  {
    const uint16_t* ap = agg + (size_t)r0 * DDIM;
#pragma unroll
    for (int it = 0; it < 8; ++it) {
      const int c = tid + 256 * it;
      const int row = c >> 5;        // 32 chunks per row
      const int k8 = (c & 31) << 3;  // 0,8,...,248
      int4 v = make_int4(0, 0, 0, 0);
      if (r0 + row < N_NODES) v = *(const int4*)(ap + (size_t)row * DDIM + k8);
      *(int4*)&As[row * APAD + k8] = v;
    }
  }
  __syncthreads();

  const uint16_t* wt_base = Wt + (size_t)(wc * 64 + l15) * DDIM + seg * 8;

  f32x4 acc[4][4] = {};
#pragma unroll
  for (int kkI = 0; kkI < 8; ++kkI) {
    const int kk = kkI * 32;
    bf16x8 a[4], b[4];
#pragma unroll
    for (int m = 0; m < 4; ++m)
      a[m] = *(const bf16x8*)&As[(m * 16 + l15) * APAD + kk + seg * 8];
#pragma unroll
    for (int n = 0; n < 4; ++n)
      b[n] = *(const bf16x8*)(wt_base + n * 16 * DDIM + kk);
#pragma unroll
    for (int m = 0; m < 4; ++m)
#pragma unroll
      for (int n = 0; n < 4; ++n)
        acc[m][n] = __builtin_amdgcn_mfma_f32_16x16x32_bf16(a[m], b[n], acc[m][n], 0, 0, 0);
  }

  // epilogue: C/D layout col = lane&15, row = seg*4 + reg
  constexpr float INV09 = 1.0f / 0.9f;
#pragma unroll
  for (int m = 0; m < 4; ++m) {
#pragma unroll
    for (int r = 0; r < 4; ++r) {
      const int lrow = m * 16 + seg * 4 + r;
      const int row = r0 + lrow;
      if (row >= N_NODES) continue;
      const float s = sdeg[lrow];
      const uint32_t w0 = mask[row * 8 + wc * 2];      // cols wc*64 .. +31
      const uint32_t w1 = mask[row * 8 + wc * 2 + 1];  // cols wc*64+32 .. +63
#pragma unroll
      for (int n = 0; n < 4; ++n) {
        const int col = wc * 64 + n * 16 + l15;
        float v = fmaxf(acc[m][n][r] * s + sbias[col], 0.0f);
        const uint32_t w = (n < 2) ? w0 : w1;
        const uint32_t bit = (uint32_t)((n & 1) * 16 + l15);
        out[(size_t)row * DDIM + col] = ((w >> bit) & 1u) ? v * INV09 : 0.0f;
      }
    }
  }
}

// ---------------------------------------------------------------------------
// ws layout (bytes; ws_size ~268 MB per harness poison fill):
//   deg_out   @ 0          (200000)
//   deg_in    @ 200000     (200000)
//   esrc      @ 400000     (12800000)  padded CSR [n][64]
//   Wt bf16   @ 13200000   (131072)
//   featb bf16@ 13331072   (25600000)
//   mask u32  @ 38931072   (1600000)
//   agg bf16  @ 40531072   (25600000)  total ~66 MB
// ---------------------------------------------------------------------------
extern "C" void kernel_launch(void* const* d_in, const int* in_sizes, int n_in,
                              void* d_out, int out_size, void* d_ws, size_t ws_size,
                              hipStream_t stream) {
  const float* feat = (const float*)d_in[0];
  const float* W = (const float*)d_in[1];
  const float* bias = (const float*)d_in[2];
  const int* src = (const int*)d_in[3];
  const int* dst = (const int*)d_in[4];
  float* out = (float*)d_out;

  char* ws = (char*)d_ws;
  int* deg_out = (int*)(ws + 0);
  int* deg_in = (int*)(ws + 200000);
  int* esrc = (int*)(ws + 400000);
  uint16_t* Wt = (uint16_t*)(ws + 13200000);
  uint16_t* featb = (uint16_t*)(ws + 13331072);
  uint32_t* mask = (uint32_t*)(ws + 38931072);
  uint16_t* agg = (uint16_t*)(ws + 40531072);

  setup_kernel<<<162, 256, 0, stream>>>(W, Wt, (int4*)d_ws);
  mega_prep_kernel<<<EDGE_BLOCKS + MASK_BLOCKS + FCONV_BLOCKS, 256, 0, stream>>>(
      feat, src, dst, deg_out, deg_in, esrc, mask, featb);
  gather_kernel<<<(N_NODES + 3) / 4, 256, 0, stream>>>(featb, deg_out, deg_in, esrc, agg);
  gemm_mfma_kernel<<<(N_NODES + 63) / 64, 256, 0, stream>>>(agg, Wt, bias, deg_in, mask, out);
}